// Round 15
// baseline (251.633 us; speedup 1.0000x reference)
//
#include <hip/hip_runtime.h>

typedef __attribute__((ext_vector_type(8))) short short8;
typedef __attribute__((ext_vector_type(4))) float f32x4;
typedef __attribute__((ext_vector_type(8))) unsigned short u16x8;
typedef __attribute__((ext_vector_type(4))) unsigned short u16x4;
typedef __attribute__((ext_vector_type(4))) unsigned int u32x4;
typedef unsigned short u16;

#define DEVINL __device__ __forceinline__

DEVINL u16 f2bf(float f) {
  unsigned u = __builtin_bit_cast(unsigned, f);
  unsigned r = (u + 0x7fffu + ((u >> 16) & 1u)) >> 16;  // RNE
  return (u16)r;
}
DEVINL float bf2f(u16 h) {
  unsigned u = ((unsigned)h) << 16;
  return __builtin_bit_cast(float, u);
}
DEVINL unsigned pk2(float a, float b) {
  return (unsigned)f2bf(a) | ((unsigned)f2bf(b) << 16);
}
// LDS tiles: [rows][64 bf16 cols] = 128 B rows = 8 chunks of 16 B.
// XOR swizzle keeps column reads conflict-free; writer & reader share it.
DEVINL int swzc(int row, int chunk) { return chunk ^ ((row ^ (row >> 3)) & 7); }
DEVINL int tile_byte(int row, int chunk) { return row * 128 + swzc(row, chunk) * 16; }

// ---------------- W conversion: P1,q,k,P4,P2,P3 -> bf16 ----------------
__global__ void kw_convert(const float* __restrict__ P1, const float* __restrict__ q,
                           const float* __restrict__ k, const float* __restrict__ P4,
                           const float* __restrict__ P2, const float* __restrict__ P3,
                           u16* __restrict__ Wbf) {
  int t = threadIdx.x;
  const float* srcs[6] = {P1, q, k, P4, P2, P3};
  for (int w = 0; w < 6; ++w)
    for (int e = t; e < 4096; e += 256) Wbf[w * 4096 + e] = f2bf(srcs[w][e]);
}

// ---------------- fused: means (in-register) + A2 + projections ----------------
// block = (T, bg), T = x*2 + h: covers A[i=0..63][s = x*512 + h*256 .. +255].
// Means computed from the f32 staging registers (no LDS re-read passes).
// A is read ONCE ever -> non-temporal loads keep L3 free for QKVA1 (attn reuse).
__global__ __launch_bounds__(512) void k_projA(
    const float* __restrict__ A, const u16* __restrict__ Wbf, u16* __restrict__ A1,
    u16* __restrict__ Q, u16* __restrict__ Km, u16* __restrict__ V,
    float* __restrict__ A2g, float* __restrict__ m2p, int g0) {
  __shared__ __align__(16) u16 tile[256 * 64];  // [s_local][i] bf16, swizzled, 32 KiB
  __shared__ __align__(16) u16 meanT[16 * 64];  // mean3[y_local][i], 2 KiB
  const int t = threadIdx.x;
  const int w = t >> 6, l = t & 63;
  const int lr = l & 15, lh = l >> 4;
  const int T = blockIdx.x, bg = blockIdx.y;
  const int x = T >> 1, h = T & 1;
  const long bglob = g0 + bg;

  // main-loop setup (wave = matrix x s-half-of-128)
  const int m = w & 3, sh = w >> 2;
  const u16* wb = Wbf + m * 4096;
  short8 wf[4][2];
#pragma unroll
  for (int ot = 0; ot < 4; ++ot)
#pragma unroll
    for (int ks = 0; ks < 2; ++ks)
      wf[ot][ks] = *(const short8*)(wb + (ot * 16 + lr) * 64 + ks * 32 + lh * 8);
  u16* outp = (m == 0) ? A1 : (m == 1) ? Q : (m == 2) ? Km : V;
  outp += (long)bg * 64 * 32768;
  const int odd = lh & 1;
  const int p8 = (lh >> 1) * 8;

  // ---- stage A -> tile; mean partials accumulate in f32 registers ----
  const int s4 = t & 31, i4 = t >> 5;
  float m3p_[2][4];  // [si][c]: sum over e (4 z's of one y)
  float m2p_[4][4];  // [c][e]: sum over si (z = (s4*4+e)&15)
  {
    const float* ap =
        A + (bglob * 64 + i4 * 4) * 32768 + (long)x * 512 + h * 256 + s4 * 4;
#pragma unroll
    for (int si = 0; si < 2; ++si) {
      f32x4 v[4];
      v[0] = __builtin_nontemporal_load((const f32x4*)(ap + si * 128));
      v[1] = __builtin_nontemporal_load((const f32x4*)(ap + si * 128 + 32768));
      v[2] = __builtin_nontemporal_load((const f32x4*)(ap + si * 128 + 65536));
      v[3] = __builtin_nontemporal_load((const f32x4*)(ap + si * 128 + 98304));
#pragma unroll
      for (int c = 0; c < 4; ++c) {
        m3p_[si][c] = v[c][0] + v[c][1] + v[c][2] + v[c][3];
#pragma unroll
        for (int e = 0; e < 4; ++e)
          m2p_[c][e] = si ? (m2p_[c][e] + v[c][e]) : v[c][e];
      }
#pragma unroll
      for (int e = 0; e < 4; ++e) {
        int s = si * 128 + s4 * 4 + e;
        u16x4 pk = {f2bf(v[0][e]), f2bf(v[1][e]), f2bf(v[2][e]), f2bf(v[3][e])};
        *(u16x4*)((char*)tile + tile_byte(s, i4 >> 1) + (i4 & 1) * 8) = pk;
      }
    }
  }
  // mean3 finalize: reduce over s4&3 (lane bits 0,1); y16 = si*8 + (s4>>2)
  {
#pragma unroll
    for (int si = 0; si < 2; ++si)
#pragma unroll
      for (int c = 0; c < 4; ++c) {
        m3p_[si][c] += __shfl_xor(m3p_[si][c], 1);
        m3p_[si][c] += __shfl_xor(m3p_[si][c], 2);
      }
    if ((s4 & 3) == 0) {
#pragma unroll
      for (int si = 0; si < 2; ++si) {
        int y16 = si * 8 + (s4 >> 2);
        u16x4 pk = {f2bf(m3p_[si][0] * 0.0625f), f2bf(m3p_[si][1] * 0.0625f),
                    f2bf(m3p_[si][2] * 0.0625f), f2bf(m3p_[si][3] * 0.0625f)};
        *(u16x4*)((char*)meanT + tile_byte(y16, i4 >> 1) + (i4 & 1) * 8) = pk;
      }
    }
  }
  // mean2 finalize: reduce over s4 bits 2..4 (lane masks 4,8,16); z = s4*4+e
  {
#pragma unroll
    for (int c = 0; c < 4; ++c)
#pragma unroll
      for (int e = 0; e < 4; ++e) {
        m2p_[c][e] += __shfl_xor(m2p_[c][e], 4);
        m2p_[c][e] += __shfl_xor(m2p_[c][e], 8);
        m2p_[c][e] += __shfl_xor(m2p_[c][e], 16);
      }
    if (s4 < 4) {
      float* mp = m2p + (((long)bg * 64 + x) * 2 + h) * 1024;
#pragma unroll
      for (int e = 0; e < 4; ++e) {
        f32x4 sv = {m2p_[0][e], m2p_[1][e], m2p_[2][e], m2p_[3][e]};
        *(f32x4*)(mp + (s4 * 4 + e) * 64 + i4 * 4) = sv;
      }
    }
  }
  __syncthreads();

  // ---- main: A1,Q,K,V = {P1,q,k,P4} @ A for this tile ----
  for (int stp = 0; stp < 4; ++stp) {
    const int srowE = sh * 128 + stp * 32 + lr;
    const int srowO = srowE + 16;
    short8 aE0 = *(const short8*)((const char*)tile + tile_byte(srowE, lh));
    short8 aE1 = *(const short8*)((const char*)tile + tile_byte(srowE, 4 + lh));
    short8 aO0 = *(const short8*)((const char*)tile + tile_byte(srowO, lh));
    short8 aO1 = *(const short8*)((const char*)tile + tile_byte(srowO, 4 + lh));
    const int sbase = x * 512 + h * 256 + sh * 128 + stp * 32 + odd * 16 + p8;
#pragma unroll
    for (int ot = 0; ot < 4; ++ot) {
      f32x4 accE = {0.0f, 0.0f, 0.0f, 0.0f}, accO = {0.0f, 0.0f, 0.0f, 0.0f};
      accE = __builtin_amdgcn_mfma_f32_16x16x32_bf16(aE0, wf[ot][0], accE, 0, 0, 0);
      accE = __builtin_amdgcn_mfma_f32_16x16x32_bf16(aE1, wf[ot][1], accE, 0, 0, 0);
      accO = __builtin_amdgcn_mfma_f32_16x16x32_bf16(aO0, wf[ot][0], accO, 0, 0, 0);
      accO = __builtin_amdgcn_mfma_f32_16x16x32_bf16(aO1, wf[ot][1], accO, 0, 0, 0);
      unsigned pE0 = pk2(accE[0], accE[1]), pE1 = pk2(accE[2], accE[3]);
      unsigned pO0 = pk2(accO[0], accO[1]), pO1 = pk2(accO[2], accO[3]);
      unsigned rE0 = __shfl_xor((int)pE0, 16), rE1 = __shfl_xor((int)pE1, 16);
      unsigned rO0 = __shfl_xor((int)pO0, 16), rO1 = __shfl_xor((int)pO1, 16);
      u32x4 sv;
      if (odd) sv = (u32x4){rO0, rO1, pO0, pO1};
      else     sv = (u32x4){pE0, pE1, rE0, rE1};
      *(u32x4*)(outp + (long)(ot * 16 + lr) * 32768 + sbase) = sv;
    }
  }
  __syncthreads();  // meanT (cross-wave) ready for A2

  // ---- A2 for this tile's y-range via MFMA on wave 0 ----
  if (w == 0) {
    const u16* wb2 = Wbf + 4 * 4096;  // P2
    f32x4 acc2[4];
#pragma unroll
    for (int ot = 0; ot < 4; ++ot) acc2[ot] = {0.0f, 0.0f, 0.0f, 0.0f};
#pragma unroll
    for (int ks = 0; ks < 2; ++ks) {
      short8 mf = *(const short8*)((const char*)meanT + tile_byte(lr, ks * 4 + lh));
#pragma unroll
      for (int ot = 0; ot < 4; ++ot) {
        short8 w2f = *(const short8*)(wb2 + (ot * 16 + lr) * 64 + ks * 32 + lh * 8);
        acc2[ot] = __builtin_amdgcn_mfma_f32_16x16x32_bf16(w2f, mf, acc2[ot], 0, 0, 0);
      }
    }
#pragma unroll
    for (int ot = 0; ot < 4; ++ot)
#pragma unroll
      for (int r = 0; r < 4; ++r) {
        int o = ot * 16 + lh * 4 + r;
        A2g[(((long)bg * 64 + o) * 64 + x) * 32 + h * 16 + lr] = acc2[ot][r];
      }
  }
}

// ---------------- A3 finalize: combine mean2 halves, project with P3 ----------------
__global__ __launch_bounds__(256) void k_a3fin(const float* __restrict__ m2p,
                                               const float* __restrict__ P3,
                                               float* __restrict__ A3g, int g0) {
  __shared__ float m2s[16 * 65];  // [z][i], padded
  const int t = threadIdx.x;
  const int x = blockIdx.x, bg = blockIdx.y;
  const float* mp = m2p + ((long)bg * 64 + x) * 2048;
  {
    int e = t * 4;  // e < 1024
    int z = e >> 6, i = e & 63;
    f32x4 v0 = __builtin_nontemporal_load((const f32x4*)(mp + e));
    f32x4 v1 = __builtin_nontemporal_load((const f32x4*)(mp + 1024 + e));
#pragma unroll
    for (int j = 0; j < 4; ++j) m2s[z * 65 + i + j] = (v0[j] + v1[j]) * (1.0f / 32.0f);
  }
  __syncthreads();
  const int z = t & 15, og = t >> 4;
#pragma unroll
  for (int oo = 0; oo < 4; ++oo) {
    int o = og * 4 + oo;
    float acc = 0.0f;
#pragma unroll 8
    for (int i = 0; i < 64; ++i) acc += P3[o * 64 + i] * m2s[z * 65 + i];
    A3g[(((long)bg * 64 + o) * 64 + x) * 16 + z] = acc;
  }
}

// ---------------- attention + combine + relu + BN partials ----------------
// Phase 1: Q/K staged via LDS, register prefetch, raw barriers (vmcnt undrained).
// Phase 3: dbuf Vt + shfl-transposed epilogue (u16x8 loads/stores, 64 B/row).
__global__ __launch_bounds__(256) void k_attn(const u16* __restrict__ Qg,
                                              const u16* __restrict__ Kg,
                                              const u16* __restrict__ Vg,
                                              const u16* __restrict__ A1g,
                                              const float* __restrict__ A2g,
                                              const float* __restrict__ A3g,
                                              u16* __restrict__ outbf,
                                              float* __restrict__ partials, int g0) {
  __shared__ __align__(16) u16 Qc[4096], Kc[4096];
  __shared__ __align__(16) u16 Vt[2][4096];
  __shared__ __align__(16) u16 An[4096];
  __shared__ float red[8];
  const int t = threadIdx.x, w = t >> 6, l = t & 63;
  const int lr = l & 15, lh = l >> 4;
  const int c = blockIdx.x, bg = blockIdx.y;
  const long bglob = g0 + bg;
  const long base = ((long)bg * 64 + c) * 32768;
  const u16* Qp = Qg + base;
  const u16* Kp = Kg + base;
  const u16* Vp = Vg + base;
  const u16* A1p = A1g + base;

  const int m4 = t & 15, y4 = t >> 4;
  const int odd = lh & 1;
  const int p8 = (lh >> 1) * 8;

  // issue V chunk 0 loads now; they fly under the whole QK^T phase
  u16x4 vr[4];
#pragma unroll
  for (int r = 0; r < 4; ++r)
    vr[r] = *(const u16x4*)(Vp + (y4 * 4 + r) * 512 + m4 * 4);

  // ---- phase 1: Alpha = Q K^T, staged Q/K with register prefetch ----
  f32x4 accA[4];
#pragma unroll
  for (int yt = 0; yt < 4; ++yt) accA[yt] = {0.0f, 0.0f, 0.0f, 0.0f};

  const int srow = t >> 3, scc = t & 7;
  u16x8 qpre[2], kpre[2];
#pragma unroll
  for (int it = 0; it < 2; ++it) {
    int row = srow + it * 32;
    int gch = scc ^ ((row ^ (row >> 3)) & 7);  // pre-swizzled global chunk
    qpre[it] = *(const u16x8*)(Qp + row * 512 + gch * 8);
    kpre[it] = *(const u16x8*)(Kp + row * 512 + gch * 8);
  }
  for (int mc = 0; mc < 8; ++mc) {
#pragma unroll
    for (int it = 0; it < 2; ++it) {
      int row = srow + it * 32;
      *(u16x8*)((char*)Qc + row * 128 + scc * 16) = qpre[it];
      *(u16x8*)((char*)Kc + row * 128 + scc * 16) = kpre[it];
    }
    asm volatile("s_waitcnt lgkmcnt(0)" ::: "memory");
    __builtin_amdgcn_s_barrier();
    __builtin_amdgcn_sched_barrier(0);
    // prefetch next chunk while MFMAs run (vmcnt not drained by barriers)
    if (mc < 7) {
      const int nc = (mc + 1) * 64;
#pragma unroll
      for (int it = 0; it < 2; ++it) {
        int row = srow + it * 32;
        int gch = scc ^ ((row ^ (row >> 3)) & 7);
        qpre[it] = *(const u16x8*)(Qp + row * 512 + nc + gch * 8);
        kpre[it] = *(const u16x8*)(Kp + row * 512 + nc + gch * 8);
      }
    }
    short8 qf[2];
#pragma unroll
    for (int ks = 0; ks < 2; ++ks)
      qf[ks] = *(const short8*)((const char*)Qc + tile_byte(16 * w + lr, ks * 4 + lh));
#pragma unroll
    for (int ks = 0; ks < 2; ++ks)
#pragma unroll
      for (int yt = 0; yt < 4; ++yt) {
        short8 kf = *(const short8*)((const char*)Kc + tile_byte(yt * 16 + lr, ks * 4 + lh));
        accA[yt] = __builtin_amdgcn_mfma_f32_16x16x32_bf16(qf[ks], kf, accA[yt], 0, 0, 0);
      }
    asm volatile("s_waitcnt lgkmcnt(0)" ::: "memory");  // drain frag reads
    __builtin_amdgcn_s_barrier();
    __builtin_amdgcn_sched_barrier(0);
  }

  // ---- phase 2: row L2-norm + Alpha_norm -> An (wave-private rows) ----
  float rsq[4];
#pragma unroll
  for (int r = 0; r < 4; ++r) {
    float s = 0.0f;
#pragma unroll
    for (int yt = 0; yt < 4; ++yt) s += accA[yt][r] * accA[yt][r];
#pragma unroll
    for (int msk = 1; msk < 16; msk <<= 1) s += __shfl_xor(s, msk);
    rsq[r] = rsqrtf(s);
  }
#pragma unroll
  for (int yt = 0; yt < 4; ++yt)
#pragma unroll
    for (int r = 0; r < 4; ++r) {
      int xr = 16 * w + 4 * lh + r;
      int y = yt * 16 + lr;
      *(u16*)((char*)An + xr * 128 + swzc(xr, y >> 3) * 16 + (y & 7) * 2) =
          f2bf(fabsf(accA[yt][r]) * rsq[r]);
    }

  // ---- phase 3: Y^T = V_t * An^T, dbuf Vt, shfl-transposed fused epilogue ----
  float ls = 0.0f, lsq = 0.0f;
  const float* A2p = A2g + ((long)bg * 64 + c) * 2048;  // [x][y]
  const float* A3p = A3g + ((long)bg * 64 + c) * 1024;  // [x][z]
  u16* outp = outbf + (bglob * 64 + c) * 32768;
  const int x = 16 * w + lr;
  // lane's z-run is mc/pair-invariant: z = p8 .. p8+7
  const f32x4 a3lo = *(const f32x4*)(A3p + x * 16 + p8);
  const f32x4 a3hi = *(const f32x4*)(A3p + x * 16 + p8 + 4);

  for (int mc = 0; mc < 8; ++mc) {
    u16* vbuf = Vt[mc & 1];
#pragma unroll
    for (int ci = 0; ci < 4; ++ci) {
      int mrow = m4 * 4 + ci;
      u16x4 pk = {vr[0][ci], vr[1][ci], vr[2][ci], vr[3][ci]};
      *(u16x4*)((char*)vbuf + tile_byte(mrow, y4 >> 1) + (y4 & 1) * 8) = pk;
    }
    // all waves' Vt writes visible; vmcnt NOT drained (prefetches keep flying)
    asm volatile("s_waitcnt lgkmcnt(0)" ::: "memory");
    __builtin_amdgcn_s_barrier();
    __builtin_amdgcn_sched_barrier(0);
    if (mc < 7) {
      const int nc = (mc + 1) * 64;
#pragma unroll
      for (int r = 0; r < 4; ++r)
        vr[r] = *(const u16x4*)(Vp + (y4 * 4 + r) * 512 + nc + m4 * 4);
    }

    f32x4 accY[4];
#pragma unroll
    for (int mt = 0; mt < 4; ++mt) accY[mt] = {0.0f, 0.0f, 0.0f, 0.0f};
#pragma unroll
    for (int ks = 0; ks < 2; ++ks) {
      short8 anf = *(const short8*)((const char*)An + tile_byte(16 * w + lr, ks * 4 + lh));
#pragma unroll
      for (int mt = 0; mt < 4; ++mt) {
        short8 vf = *(const short8*)((const char*)vbuf + tile_byte(mt * 16 + lr, ks * 4 + lh));
        accY[mt] = __builtin_amdgcn_mfma_f32_16x16x32_bf16(vf, anf, accY[mt], 0, 0, 0);
      }
    }
    // epilogue: shfl-transpose accY f32 (values & order identical)
#pragma unroll
    for (int pair = 0; pair < 2; ++pair) {
      f32x4 aE = accY[2 * pair], aO = accY[2 * pair + 1];
      f32x4 rE, rO;
#pragma unroll
      for (int j = 0; j < 4; ++j) {
        rE[j] = __shfl_xor(aE[j], 16);
        rO[j] = __shfl_xor(aO[j], 16);
      }
      const int mb = mc * 64 + pair * 32 + odd * 16 + p8;
      const float a2v = A2p[x * 32 + (mb >> 4)];
      u16x8 a1v = *(const u16x8*)(A1p + x * 512 + mb);
      u16x8 o;
#pragma unroll
      for (int r = 0; r < 8; ++r) {
        float yv = (r < 4) ? (odd ? rO[r] : aE[r]) : (odd ? aO[r - 4] : rE[r - 4]);
        float a3v = (r < 4) ? a3lo[r] : a3hi[r - 4];
        float val = bf2f(a1v[r]) + 0.1f * (a2v + a3v + yv);
        val = fmaxf(val, 0.0f);
        o[r] = f2bf(val);
        ls += val;
        lsq += val * val;
      }
      *(u16x8*)(outp + x * 512 + mb) = o;
    }
  }

  // ---- phase 4: deterministic block reduction of BN partials ----
#pragma unroll
  for (int off = 32; off > 0; off >>= 1) {
    ls += __shfl_xor(ls, off);
    lsq += __shfl_xor(lsq, off);
  }
  if (l == 0) {
    red[w] = ls;
    red[4 + w] = lsq;
  }
  __syncthreads();
  if (t == 0) {
    partials[2 * (bglob * 64 + c) + 0] = red[0] + red[1] + red[2] + red[3];
    partials[2 * (bglob * 64 + c) + 1] = red[4] + red[5] + red[6] + red[7];
  }
}

// ---------------- BN stats finalize ----------------
__global__ void k_stats(const float* __restrict__ partials, const float* __restrict__ gamma,
                        const float* __restrict__ beta, float* __restrict__ sb) {
  int c = threadIdx.x;
  if (c >= 64) return;
  float S = 0.0f, SQ = 0.0f;
  for (int b = 0; b < 16; ++b) {
    S += partials[2 * (b * 64 + c) + 0];
    SQ += partials[2 * (b * 64 + c) + 1];
  }
  const float N = 524288.0f;
  float mean = S / N;
  float var = SQ / N - mean * mean;
  float rs = rsqrtf(var + 1e-5f);
  float scale = gamma[c] * rs;
  sb[c] = scale;
  sb[64 + c] = beta[c] - mean * scale;
}

// ---------------- BN affine: bf16 in -> f32 out (streaming, no L3 alloc) ----------------
__global__ void k_bn(const u16* __restrict__ outbf, float* __restrict__ out,
                     const float* __restrict__ sb) {
  long idx = ((long)blockIdx.x * 256 + threadIdx.x) * 8;
  int c = (int)((idx >> 15) & 63);
  float scale = sb[c], bias = sb[64 + c];
  u16x8 v = __builtin_nontemporal_load((const u16x8*)(outbf + idx));
  f32x4 o0, o1;
#pragma unroll
  for (int r = 0; r < 4; ++r) {
    o0[r] = bf2f(v[r]) * scale + bias;
    o1[r] = bf2f(v[4 + r]) * scale + bias;
  }
  __builtin_nontemporal_store(o0, (f32x4*)(out + idx));
  __builtin_nontemporal_store(o1, (f32x4*)(out + idx + 4));
}

extern "C" void kernel_launch(void* const* d_in, const int* in_sizes, int n_in, void* d_out,
                              int out_size, void* d_ws, size_t ws_size, hipStream_t stream) {
  (void)in_sizes; (void)n_in; (void)out_size;
  const float* A = (const float*)d_in[0];
  const float* P1 = (const float*)d_in[1];
  const float* P2 = (const float*)d_in[2];
  const float* P3 = (const float*)d_in[3];
  const float* P4 = (const float*)d_in[4];
  const float* q = (const float*)d_in[5];
  const float* k = (const float*)d_in[6];
  const float* gamma = (const float*)d_in[7];
  const float* beta = (const float*)d_in[8];
  float* out = (float*)d_out;
  char* ws = (char*)d_ws;

  u16* Wbf = (u16*)ws;                     // 48 KiB (6 matrices)
  float* partials = (float*)(ws + 49152);  // 8 KiB
  float* sb = (float*)(ws + 57344);        // 512 B
  const size_t GR = 65536;
  const size_t OUTBF = (size_t)16 * 64 * 32768 * 2;  // 64 MiB pre-BN bf16
  u16* outbf = (u16*)(ws + GR);
  const size_t SZ_M = (size_t)64 * 32768 * 2;      // 4 MiB per batch per matrix (bf16)
  const size_t SZ_A2 = (size_t)64 * 64 * 32 * 4;   // 512 KiB
  const size_t SZ_A3 = (size_t)64 * 64 * 16 * 4;   // 256 KiB
  const size_t SZ_M2 = (size_t)64 * 2 * 16 * 64 * 4;  // 512 KiB (mean2 partials)
  const size_t perb = 4 * SZ_M + SZ_A2 + SZ_A3 + SZ_M2;  // ~17.25 MiB
  const size_t base0 = GR + OUTBF;
  int G = 1;
  if (ws_size > base0 + perb) G = (int)((ws_size - base0) / perb);
  // G=8: group working set stays L3-resident so k_attn reads hit L3 (R10: -33 us).
  if (G > 8) G = 8;
  if (G < 1) G = 1;

  u16* A1 = (u16*)(ws + base0);
  u16* Qw = (u16*)(ws + base0 + (size_t)G * SZ_M);
  u16* Kw = (u16*)(ws + base0 + (size_t)G * SZ_M * 2);
  u16* Vw = (u16*)(ws + base0 + (size_t)G * SZ_M * 3);
  float* A2 = (float*)(ws + base0 + (size_t)G * SZ_M * 4);
  float* A3 = (float*)((char*)A2 + (size_t)G * SZ_A2);
  float* m2p = (float*)((char*)A3 + (size_t)G * SZ_A3);

  kw_convert<<<1, 256, 0, stream>>>(P1, q, k, P4, P2, P3, Wbf);
  for (int g0 = 0; g0 < 16; g0 += G) {
    int Gc = (16 - g0) < G ? (16 - g0) : G;
    k_projA<<<dim3(128, Gc), 512, 0, stream>>>(A, Wbf, A1, Qw, Kw, Vw, A2, m2p, g0);
    k_a3fin<<<dim3(64, Gc), 256, 0, stream>>>(m2p, P3, A3, g0);
    k_attn<<<dim3(64, Gc), 256, 0, stream>>>(Qw, Kw, Vw, A1, A2, A3, outbf, partials, g0);
  }
  k_stats<<<1, 64, 0, stream>>>(partials, gamma, beta, sb);
  k_bn<<<16384, 256, 0, stream>>>(outbf, out, sb);
}

// Round 16
// 239.921 us; speedup vs baseline: 1.0488x; 1.0488x over previous
//
#include <hip/hip_runtime.h>

typedef __attribute__((ext_vector_type(8))) short short8;
typedef __attribute__((ext_vector_type(4))) float f32x4;
typedef __attribute__((ext_vector_type(8))) unsigned short u16x8;
typedef __attribute__((ext_vector_type(4))) unsigned short u16x4;
typedef __attribute__((ext_vector_type(4))) unsigned int u32x4;
typedef unsigned short u16;

#define DEVINL __device__ __forceinline__

DEVINL u16 f2bf(float f) {
  unsigned u = __builtin_bit_cast(unsigned, f);
  unsigned r = (u + 0x7fffu + ((u >> 16) & 1u)) >> 16;  // RNE
  return (u16)r;
}
DEVINL float bf2f(u16 h) {
  unsigned u = ((unsigned)h) << 16;
  return __builtin_bit_cast(float, u);
}
DEVINL unsigned pk2(float a, float b) {
  return (unsigned)f2bf(a) | ((unsigned)f2bf(b) << 16);
}
// LDS tiles: [rows][64 bf16 cols] = 128 B rows = 8 chunks of 16 B.
// XOR swizzle keeps column reads conflict-free; writer & reader share it.
DEVINL int swzc(int row, int chunk) { return chunk ^ ((row ^ (row >> 3)) & 7); }
DEVINL int tile_byte(int row, int chunk) { return row * 128 + swzc(row, chunk) * 16; }

// ---------------- W conversion: P1,q,k,P4,P2,P3 -> bf16 ----------------
__global__ void kw_convert(const float* __restrict__ P1, const float* __restrict__ q,
                           const float* __restrict__ k, const float* __restrict__ P4,
                           const float* __restrict__ P2, const float* __restrict__ P3,
                           u16* __restrict__ Wbf) {
  int t = threadIdx.x;
  const float* srcs[6] = {P1, q, k, P4, P2, P3};
  for (int w = 0; w < 6; ++w)
    for (int e = t; e < 4096; e += 256) Wbf[w * 4096 + e] = f2bf(srcs[w][e]);
}

// ---------------- fused: means (in-register) + A2 + projections ----------------
// block = (T, bg), T = x*2 + h: covers A[i=0..63][s = x*512 + h*256 .. +255].
// Means computed from the f32 staging registers (no LDS re-read passes).
// Plain (cached) A loads: L3 retains ~half of A across graph replays (R15
// measured NT loads cost +11.5 us by discarding that reuse).
__global__ __launch_bounds__(512) void k_projA(
    const float* __restrict__ A, const u16* __restrict__ Wbf, u16* __restrict__ A1,
    u16* __restrict__ Q, u16* __restrict__ Km, u16* __restrict__ V,
    float* __restrict__ A2g, float* __restrict__ m2p, int g0) {
  __shared__ __align__(16) u16 tile[256 * 64];  // [s_local][i] bf16, swizzled, 32 KiB
  __shared__ __align__(16) u16 meanT[16 * 64];  // mean3[y_local][i], 2 KiB
  const int t = threadIdx.x;
  const int w = t >> 6, l = t & 63;
  const int lr = l & 15, lh = l >> 4;
  const int T = blockIdx.x, bg = blockIdx.y;
  const int x = T >> 1, h = T & 1;
  const long bglob = g0 + bg;

  // main-loop setup (wave = matrix x s-half-of-128)
  const int m = w & 3, sh = w >> 2;
  const u16* wb = Wbf + m * 4096;
  short8 wf[4][2];
#pragma unroll
  for (int ot = 0; ot < 4; ++ot)
#pragma unroll
    for (int ks = 0; ks < 2; ++ks)
      wf[ot][ks] = *(const short8*)(wb + (ot * 16 + lr) * 64 + ks * 32 + lh * 8);
  u16* outp = (m == 0) ? A1 : (m == 1) ? Q : (m == 2) ? Km : V;
  outp += (long)bg * 64 * 32768;
  const int odd = lh & 1;
  const int p8 = (lh >> 1) * 8;

  // ---- stage A -> tile; mean partials accumulate in f32 registers ----
  const int s4 = t & 31, i4 = t >> 5;
  float m3p_[2][4];  // [si][c]: sum over e (4 z's of one y)
  float m2p_[4][4];  // [c][e]: sum over si (z = (s4*4+e)&15)
  {
    const float* ap =
        A + (bglob * 64 + i4 * 4) * 32768 + (long)x * 512 + h * 256 + s4 * 4;
#pragma unroll
    for (int si = 0; si < 2; ++si) {
      f32x4 v[4];
      v[0] = *(const f32x4*)(ap + si * 128);
      v[1] = *(const f32x4*)(ap + si * 128 + 32768);
      v[2] = *(const f32x4*)(ap + si * 128 + 65536);
      v[3] = *(const f32x4*)(ap + si * 128 + 98304);
#pragma unroll
      for (int c = 0; c < 4; ++c) {
        m3p_[si][c] = v[c][0] + v[c][1] + v[c][2] + v[c][3];
#pragma unroll
        for (int e = 0; e < 4; ++e)
          m2p_[c][e] = si ? (m2p_[c][e] + v[c][e]) : v[c][e];
      }
#pragma unroll
      for (int e = 0; e < 4; ++e) {
        int s = si * 128 + s4 * 4 + e;
        u16x4 pk = {f2bf(v[0][e]), f2bf(v[1][e]), f2bf(v[2][e]), f2bf(v[3][e])};
        *(u16x4*)((char*)tile + tile_byte(s, i4 >> 1) + (i4 & 1) * 8) = pk;
      }
    }
  }
  // mean3 finalize: reduce over s4&3 (lane bits 0,1); y16 = si*8 + (s4>>2)
  {
#pragma unroll
    for (int si = 0; si < 2; ++si)
#pragma unroll
      for (int c = 0; c < 4; ++c) {
        m3p_[si][c] += __shfl_xor(m3p_[si][c], 1);
        m3p_[si][c] += __shfl_xor(m3p_[si][c], 2);
      }
    if ((s4 & 3) == 0) {
#pragma unroll
      for (int si = 0; si < 2; ++si) {
        int y16 = si * 8 + (s4 >> 2);
        u16x4 pk = {f2bf(m3p_[si][0] * 0.0625f), f2bf(m3p_[si][1] * 0.0625f),
                    f2bf(m3p_[si][2] * 0.0625f), f2bf(m3p_[si][3] * 0.0625f)};
        *(u16x4*)((char*)meanT + tile_byte(y16, i4 >> 1) + (i4 & 1) * 8) = pk;
      }
    }
  }
  // mean2 finalize: reduce over s4 bits 2..4 (lane masks 4,8,16); z = s4*4+e
  {
#pragma unroll
    for (int c = 0; c < 4; ++c)
#pragma unroll
      for (int e = 0; e < 4; ++e) {
        m2p_[c][e] += __shfl_xor(m2p_[c][e], 4);
        m2p_[c][e] += __shfl_xor(m2p_[c][e], 8);
        m2p_[c][e] += __shfl_xor(m2p_[c][e], 16);
      }
    if (s4 < 4) {
      float* mp = m2p + (((long)bg * 64 + x) * 2 + h) * 1024;
#pragma unroll
      for (int e = 0; e < 4; ++e) {
        f32x4 sv = {m2p_[0][e], m2p_[1][e], m2p_[2][e], m2p_[3][e]};
        *(f32x4*)(mp + (s4 * 4 + e) * 64 + i4 * 4) = sv;
      }
    }
  }
  __syncthreads();

  // ---- main: A1,Q,K,V = {P1,q,k,P4} @ A for this tile ----
  for (int stp = 0; stp < 4; ++stp) {
    const int srowE = sh * 128 + stp * 32 + lr;
    const int srowO = srowE + 16;
    short8 aE0 = *(const short8*)((const char*)tile + tile_byte(srowE, lh));
    short8 aE1 = *(const short8*)((const char*)tile + tile_byte(srowE, 4 + lh));
    short8 aO0 = *(const short8*)((const char*)tile + tile_byte(srowO, lh));
    short8 aO1 = *(const short8*)((const char*)tile + tile_byte(srowO, 4 + lh));
    const int sbase = x * 512 + h * 256 + sh * 128 + stp * 32 + odd * 16 + p8;
#pragma unroll
    for (int ot = 0; ot < 4; ++ot) {
      f32x4 accE = {0.0f, 0.0f, 0.0f, 0.0f}, accO = {0.0f, 0.0f, 0.0f, 0.0f};
      accE = __builtin_amdgcn_mfma_f32_16x16x32_bf16(aE0, wf[ot][0], accE, 0, 0, 0);
      accE = __builtin_amdgcn_mfma_f32_16x16x32_bf16(aE1, wf[ot][1], accE, 0, 0, 0);
      accO = __builtin_amdgcn_mfma_f32_16x16x32_bf16(aO0, wf[ot][0], accO, 0, 0, 0);
      accO = __builtin_amdgcn_mfma_f32_16x16x32_bf16(aO1, wf[ot][1], accO, 0, 0, 0);
      unsigned pE0 = pk2(accE[0], accE[1]), pE1 = pk2(accE[2], accE[3]);
      unsigned pO0 = pk2(accO[0], accO[1]), pO1 = pk2(accO[2], accO[3]);
      unsigned rE0 = __shfl_xor((int)pE0, 16), rE1 = __shfl_xor((int)pE1, 16);
      unsigned rO0 = __shfl_xor((int)pO0, 16), rO1 = __shfl_xor((int)pO1, 16);
      u32x4 sv;
      if (odd) sv = (u32x4){rO0, rO1, pO0, pO1};
      else     sv = (u32x4){pE0, pE1, rE0, rE1};
      *(u32x4*)(outp + (long)(ot * 16 + lr) * 32768 + sbase) = sv;
    }
  }
  __syncthreads();  // meanT (cross-wave) ready for A2

  // ---- A2 for this tile's y-range via MFMA on wave 0 ----
  if (w == 0) {
    const u16* wb2 = Wbf + 4 * 4096;  // P2
    f32x4 acc2[4];
#pragma unroll
    for (int ot = 0; ot < 4; ++ot) acc2[ot] = {0.0f, 0.0f, 0.0f, 0.0f};
#pragma unroll
    for (int ks = 0; ks < 2; ++ks) {
      short8 mf = *(const short8*)((const char*)meanT + tile_byte(lr, ks * 4 + lh));
#pragma unroll
      for (int ot = 0; ot < 4; ++ot) {
        short8 w2f = *(const short8*)(wb2 + (ot * 16 + lr) * 64 + ks * 32 + lh * 8);
        acc2[ot] = __builtin_amdgcn_mfma_f32_16x16x32_bf16(w2f, mf, acc2[ot], 0, 0, 0);
      }
    }
#pragma unroll
    for (int ot = 0; ot < 4; ++ot)
#pragma unroll
      for (int r = 0; r < 4; ++r) {
        int o = ot * 16 + lh * 4 + r;
        A2g[(((long)bg * 64 + o) * 64 + x) * 32 + h * 16 + lr] = acc2[ot][r];
      }
  }
}

// ---------------- A3 finalize: combine mean2 halves, project with P3 ----------------
__global__ __launch_bounds__(256) void k_a3fin(const float* __restrict__ m2p,
                                               const float* __restrict__ P3,
                                               float* __restrict__ A3g, int g0) {
  __shared__ float m2s[16 * 65];  // [z][i], padded
  const int t = threadIdx.x;
  const int x = blockIdx.x, bg = blockIdx.y;
  const float* mp = m2p + ((long)bg * 64 + x) * 2048;
  {
    int e = t * 4;  // e < 1024
    int z = e >> 6, i = e & 63;
    f32x4 v0 = *(const f32x4*)(mp + e);
    f32x4 v1 = *(const f32x4*)(mp + 1024 + e);
#pragma unroll
    for (int j = 0; j < 4; ++j) m2s[z * 65 + i + j] = (v0[j] + v1[j]) * (1.0f / 32.0f);
  }
  __syncthreads();
  const int z = t & 15, og = t >> 4;
#pragma unroll
  for (int oo = 0; oo < 4; ++oo) {
    int o = og * 4 + oo;
    float acc = 0.0f;
#pragma unroll 8
    for (int i = 0; i < 64; ++i) acc += P3[o * 64 + i] * m2s[z * 65 + i];
    A3g[(((long)bg * 64 + o) * 64 + x) * 16 + z] = acc;
  }
}

// ---------------- attention + combine + relu + BN partials ----------------
// Phase 1: Q/K staged via LDS, register prefetch, raw barriers (vmcnt undrained).
// Phase 3: dbuf Vt + shfl-transposed epilogue (u16x8 loads/stores, 64 B/row).
__global__ __launch_bounds__(256) void k_attn(const u16* __restrict__ Qg,
                                              const u16* __restrict__ Kg,
                                              const u16* __restrict__ Vg,
                                              const u16* __restrict__ A1g,
                                              const float* __restrict__ A2g,
                                              const float* __restrict__ A3g,
                                              u16* __restrict__ outbf,
                                              float* __restrict__ partials, int g0) {
  __shared__ __align__(16) u16 Qc[4096], Kc[4096];
  __shared__ __align__(16) u16 Vt[2][4096];
  __shared__ __align__(16) u16 An[4096];
  __shared__ float red[8];
  const int t = threadIdx.x, w = t >> 6, l = t & 63;
  const int lr = l & 15, lh = l >> 4;
  const int c = blockIdx.x, bg = blockIdx.y;
  const long bglob = g0 + bg;
  const long base = ((long)bg * 64 + c) * 32768;
  const u16* Qp = Qg + base;
  const u16* Kp = Kg + base;
  const u16* Vp = Vg + base;
  const u16* A1p = A1g + base;

  const int m4 = t & 15, y4 = t >> 4;
  const int odd = lh & 1;
  const int p8 = (lh >> 1) * 8;

  // issue V chunk 0 loads now; they fly under the whole QK^T phase
  u16x4 vr[4];
#pragma unroll
  for (int r = 0; r < 4; ++r)
    vr[r] = *(const u16x4*)(Vp + (y4 * 4 + r) * 512 + m4 * 4);

  // ---- phase 1: Alpha = Q K^T, staged Q/K with register prefetch ----
  f32x4 accA[4];
#pragma unroll
  for (int yt = 0; yt < 4; ++yt) accA[yt] = {0.0f, 0.0f, 0.0f, 0.0f};

  const int srow = t >> 3, scc = t & 7;
  u16x8 qpre[2], kpre[2];
#pragma unroll
  for (int it = 0; it < 2; ++it) {
    int row = srow + it * 32;
    int gch = scc ^ ((row ^ (row >> 3)) & 7);  // pre-swizzled global chunk
    qpre[it] = *(const u16x8*)(Qp + row * 512 + gch * 8);
    kpre[it] = *(const u16x8*)(Kp + row * 512 + gch * 8);
  }
  for (int mc = 0; mc < 8; ++mc) {
#pragma unroll
    for (int it = 0; it < 2; ++it) {
      int row = srow + it * 32;
      *(u16x8*)((char*)Qc + row * 128 + scc * 16) = qpre[it];
      *(u16x8*)((char*)Kc + row * 128 + scc * 16) = kpre[it];
    }
    asm volatile("s_waitcnt lgkmcnt(0)" ::: "memory");
    __builtin_amdgcn_s_barrier();
    __builtin_amdgcn_sched_barrier(0);
    // prefetch next chunk while MFMAs run (vmcnt not drained by barriers)
    if (mc < 7) {
      const int nc = (mc + 1) * 64;
#pragma unroll
      for (int it = 0; it < 2; ++it) {
        int row = srow + it * 32;
        int gch = scc ^ ((row ^ (row >> 3)) & 7);
        qpre[it] = *(const u16x8*)(Qp + row * 512 + nc + gch * 8);
        kpre[it] = *(const u16x8*)(Kp + row * 512 + nc + gch * 8);
      }
    }
    short8 qf[2];
#pragma unroll
    for (int ks = 0; ks < 2; ++ks)
      qf[ks] = *(const short8*)((const char*)Qc + tile_byte(16 * w + lr, ks * 4 + lh));
#pragma unroll
    for (int ks = 0; ks < 2; ++ks)
#pragma unroll
      for (int yt = 0; yt < 4; ++yt) {
        short8 kf = *(const short8*)((const char*)Kc + tile_byte(yt * 16 + lr, ks * 4 + lh));
        accA[yt] = __builtin_amdgcn_mfma_f32_16x16x32_bf16(qf[ks], kf, accA[yt], 0, 0, 0);
      }
    asm volatile("s_waitcnt lgkmcnt(0)" ::: "memory");  // drain frag reads
    __builtin_amdgcn_s_barrier();
    __builtin_amdgcn_sched_barrier(0);
  }

  // ---- phase 2: row L2-norm + Alpha_norm -> An (wave-private rows) ----
  float rsq[4];
#pragma unroll
  for (int r = 0; r < 4; ++r) {
    float s = 0.0f;
#pragma unroll
    for (int yt = 0; yt < 4; ++yt) s += accA[yt][r] * accA[yt][r];
#pragma unroll
    for (int msk = 1; msk < 16; msk <<= 1) s += __shfl_xor(s, msk);
    rsq[r] = rsqrtf(s);
  }
#pragma unroll
  for (int yt = 0; yt < 4; ++yt)
#pragma unroll
    for (int r = 0; r < 4; ++r) {
      int xr = 16 * w + 4 * lh + r;
      int y = yt * 16 + lr;
      *(u16*)((char*)An + xr * 128 + swzc(xr, y >> 3) * 16 + (y & 7) * 2) =
          f2bf(fabsf(accA[yt][r]) * rsq[r]);
    }

  // ---- phase 3: Y^T = V_t * An^T, dbuf Vt, shfl-transposed fused epilogue ----
  float ls = 0.0f, lsq = 0.0f;
  const float* A2p = A2g + ((long)bg * 64 + c) * 2048;  // [x][y]
  const float* A3p = A3g + ((long)bg * 64 + c) * 1024;  // [x][z]
  u16* outp = outbf + (bglob * 64 + c) * 32768;
  const int x = 16 * w + lr;
  // lane's z-run is mc/pair-invariant: z = p8 .. p8+7
  const f32x4 a3lo = *(const f32x4*)(A3p + x * 16 + p8);
  const f32x4 a3hi = *(const f32x4*)(A3p + x * 16 + p8 + 4);

  for (int mc = 0; mc < 8; ++mc) {
    u16* vbuf = Vt[mc & 1];
#pragma unroll
    for (int ci = 0; ci < 4; ++ci) {
      int mrow = m4 * 4 + ci;
      u16x4 pk = {vr[0][ci], vr[1][ci], vr[2][ci], vr[3][ci]};
      *(u16x4*)((char*)vbuf + tile_byte(mrow, y4 >> 1) + (y4 & 1) * 8) = pk;
    }
    // all waves' Vt writes visible; vmcnt NOT drained (prefetches keep flying)
    asm volatile("s_waitcnt lgkmcnt(0)" ::: "memory");
    __builtin_amdgcn_s_barrier();
    __builtin_amdgcn_sched_barrier(0);
    if (mc < 7) {
      const int nc = (mc + 1) * 64;
#pragma unroll
      for (int r = 0; r < 4; ++r)
        vr[r] = *(const u16x4*)(Vp + (y4 * 4 + r) * 512 + nc + m4 * 4);
    }

    f32x4 accY[4];
#pragma unroll
    for (int mt = 0; mt < 4; ++mt) accY[mt] = {0.0f, 0.0f, 0.0f, 0.0f};
#pragma unroll
    for (int ks = 0; ks < 2; ++ks) {
      short8 anf = *(const short8*)((const char*)An + tile_byte(16 * w + lr, ks * 4 + lh));
#pragma unroll
      for (int mt = 0; mt < 4; ++mt) {
        short8 vf = *(const short8*)((const char*)vbuf + tile_byte(mt * 16 + lr, ks * 4 + lh));
        accY[mt] = __builtin_amdgcn_mfma_f32_16x16x32_bf16(vf, anf, accY[mt], 0, 0, 0);
      }
    }
    // epilogue: shfl-transpose accY f32 (values & order identical)
#pragma unroll
    for (int pair = 0; pair < 2; ++pair) {
      f32x4 aE = accY[2 * pair], aO = accY[2 * pair + 1];
      f32x4 rE, rO;
#pragma unroll
      for (int j = 0; j < 4; ++j) {
        rE[j] = __shfl_xor(aE[j], 16);
        rO[j] = __shfl_xor(aO[j], 16);
      }
      const int mb = mc * 64 + pair * 32 + odd * 16 + p8;
      const float a2v = A2p[x * 32 + (mb >> 4)];
      u16x8 a1v = *(const u16x8*)(A1p + x * 512 + mb);
      u16x8 o;
#pragma unroll
      for (int r = 0; r < 8; ++r) {
        float yv = (r < 4) ? (odd ? rO[r] : aE[r]) : (odd ? aO[r - 4] : rE[r - 4]);
        float a3v = (r < 4) ? a3lo[r] : a3hi[r - 4];
        float val = bf2f(a1v[r]) + 0.1f * (a2v + a3v + yv);
        val = fmaxf(val, 0.0f);
        o[r] = f2bf(val);
        ls += val;
        lsq += val * val;
      }
      *(u16x8*)(outp + x * 512 + mb) = o;
    }
  }

  // ---- phase 4: deterministic block reduction of BN partials ----
#pragma unroll
  for (int off = 32; off > 0; off >>= 1) {
    ls += __shfl_xor(ls, off);
    lsq += __shfl_xor(lsq, off);
  }
  if (l == 0) {
    red[w] = ls;
    red[4 + w] = lsq;
  }
  __syncthreads();
  if (t == 0) {
    partials[2 * (bglob * 64 + c) + 0] = red[0] + red[1] + red[2] + red[3];
    partials[2 * (bglob * 64 + c) + 1] = red[4] + red[5] + red[6] + red[7];
  }
}

// ---------------- BN stats finalize ----------------
__global__ void k_stats(const float* __restrict__ partials, const float* __restrict__ gamma,
                        const float* __restrict__ beta, float* __restrict__ sb) {
  int c = threadIdx.x;
  if (c >= 64) return;
  float S = 0.0f, SQ = 0.0f;
  for (int b = 0; b < 16; ++b) {
    S += partials[2 * (b * 64 + c) + 0];
    SQ += partials[2 * (b * 64 + c) + 1];
  }
  const float N = 524288.0f;
  float mean = S / N;
  float var = SQ / N - mean * mean;
  float rs = rsqrtf(var + 1e-5f);
  float scale = gamma[c] * rs;
  sb[c] = scale;
  sb[64 + c] = beta[c] - mean * scale;
}

// ---------------- BN affine: bf16 in -> f32 out ----------------
__global__ void k_bn(const u16* __restrict__ outbf, float* __restrict__ out,
                     const float* __restrict__ sb) {
  long idx = ((long)blockIdx.x * 256 + threadIdx.x) * 8;
  int c = (int)((idx >> 15) & 63);
  float scale = sb[c], bias = sb[64 + c];
  u16x8 v = *(const u16x8*)(outbf + idx);
  f32x4 o0, o1;
#pragma unroll
  for (int r = 0; r < 4; ++r) {
    o0[r] = bf2f(v[r]) * scale + bias;
    o1[r] = bf2f(v[4 + r]) * scale + bias;
  }
  *(f32x4*)(out + idx) = o0;
  *(f32x4*)(out + idx + 4) = o1;
}

extern "C" void kernel_launch(void* const* d_in, const int* in_sizes, int n_in, void* d_out,
                              int out_size, void* d_ws, size_t ws_size, hipStream_t stream) {
  (void)in_sizes; (void)n_in; (void)out_size;
  const float* A = (const float*)d_in[0];
  const float* P1 = (const float*)d_in[1];
  const float* P2 = (const float*)d_in[2];
  const float* P3 = (const float*)d_in[3];
  const float* P4 = (const float*)d_in[4];
  const float* q = (const float*)d_in[5];
  const float* k = (const float*)d_in[6];
  const float* gamma = (const float*)d_in[7];
  const float* beta = (const float*)d_in[8];
  float* out = (float*)d_out;
  char* ws = (char*)d_ws;

  u16* Wbf = (u16*)ws;                     // 48 KiB (6 matrices)
  float* partials = (float*)(ws + 49152);  // 8 KiB
  float* sb = (float*)(ws + 57344);        // 512 B
  const size_t GR = 65536;
  const size_t OUTBF = (size_t)16 * 64 * 32768 * 2;  // 64 MiB pre-BN bf16
  u16* outbf = (u16*)(ws + GR);
  const size_t SZ_M = (size_t)64 * 32768 * 2;      // 4 MiB per batch per matrix (bf16)
  const size_t SZ_A2 = (size_t)64 * 64 * 32 * 4;   // 512 KiB
  const size_t SZ_A3 = (size_t)64 * 64 * 16 * 4;   // 256 KiB
  const size_t SZ_M2 = (size_t)64 * 2 * 16 * 64 * 4;  // 512 KiB (mean2 partials)
  const size_t perb = 4 * SZ_M + SZ_A2 + SZ_A3 + SZ_M2;  // ~17.25 MiB
  const size_t base0 = GR + OUTBF;
  int G = 1;
  if (ws_size > base0 + perb) G = (int)((ws_size - base0) / perb);
  // G=8: group working set stays L3-resident so k_attn reads hit L3 (R10: -33 us).
  if (G > 8) G = 8;
  if (G < 1) G = 1;

  u16* A1 = (u16*)(ws + base0);
  u16* Qw = (u16*)(ws + base0 + (size_t)G * SZ_M);
  u16* Kw = (u16*)(ws + base0 + (size_t)G * SZ_M * 2);
  u16* Vw = (u16*)(ws + base0 + (size_t)G * SZ_M * 3);
  float* A2 = (float*)(ws + base0 + (size_t)G * SZ_M * 4);
  float* A3 = (float*)((char*)A2 + (size_t)G * SZ_A2);
  float* m2p = (float*)((char*)A3 + (size_t)G * SZ_A3);

  kw_convert<<<1, 256, 0, stream>>>(P1, q, k, P4, P2, P3, Wbf);
  for (int g0 = 0; g0 < 16; g0 += G) {
    int Gc = (16 - g0) < G ? (16 - g0) : G;
    k_projA<<<dim3(128, Gc), 512, 0, stream>>>(A, Wbf, A1, Qw, Kw, Vw, A2, m2p, g0);
    k_a3fin<<<dim3(64, Gc), 256, 0, stream>>>(m2p, P3, A3, g0);
    k_attn<<<dim3(64, Gc), 256, 0, stream>>>(Qw, Kw, Vw, A1, A2, A3, outbf, partials, g0);
  }
  k_stats<<<1, 64, 0, stream>>>(partials, gamma, beta, sb);
  k_bn<<<16384, 256, 0, stream>>>(outbf, out, sb);
}